// Round 2
// baseline (2934.878 us; speedup 1.0000x reference)
//
#include <hip/hip_runtime.h>
#include <stdint.h>

#define TT 8192
#define DD 5120
#define HH 13824

typedef int v4i __attribute__((ext_vector_type(4)));

#define AS1(p) ((const __attribute__((address_space(1))) void*)(p))
#define AS3(p) ((__attribute__((address_space(3))) void*)(p))

__device__ __forceinline__ float wave_max64(float v) {
#pragma unroll
  for (int off = 32; off > 0; off >>= 1)
    v = fmaxf(v, __shfl_xor(v, off, 64));
  return v;
}
__device__ __forceinline__ int wave_sum64(int v) {
#pragma unroll
  for (int off = 32; off > 0; off >>= 1)
    v += __shfl_xor(v, off, 64);
  return v;
}

// ---------------- weight convert: int32 codes (0..255) -> int8 (code-128) ----------------
__global__ __launch_bounds__(256) void cvt_w(const int* __restrict__ w,
                                             int8_t* __restrict__ o, int n16) {
  const int4* w4 = (const int4*)w;
  int4* o4 = (int4*)o;
  int i = blockIdx.x * blockDim.x + threadIdx.x;
  int stride = gridDim.x * blockDim.x;
  for (; i < n16; i += stride) {
    int4 a = w4[(size_t)i * 4 + 0];
    int4 b = w4[(size_t)i * 4 + 1];
    int4 c = w4[(size_t)i * 4 + 2];
    int4 d = w4[(size_t)i * 4 + 3];
    int4 r;
    r.x = ((a.x - 128) & 0xff) | (((a.y - 128) & 0xff) << 8) |
          (((a.z - 128) & 0xff) << 16) | (((a.w - 128) & 0xff) << 24);
    r.y = ((b.x - 128) & 0xff) | (((b.y - 128) & 0xff) << 8) |
          (((b.z - 128) & 0xff) << 16) | (((b.w - 128) & 0xff) << 24);
    r.z = ((c.x - 128) & 0xff) | (((c.y - 128) & 0xff) << 8) |
          (((c.z - 128) & 0xff) << 16) | (((c.w - 128) & 0xff) << 24);
    r.w = ((d.x - 128) & 0xff) | (((d.y - 128) & 0xff) << 8) |
          (((d.z - 128) & 0xff) << 16) | (((d.w - 128) & 0xff) << 24);
    o4[i] = r;
  }
}

// ---------------- per-token dynamic quant of x [TT, DD] ----------------
__global__ __launch_bounds__(256) void quant_x(const float* __restrict__ x,
                                               int8_t* __restrict__ q,
                                               float* __restrict__ s_out,
                                               float* __restrict__ sum_out) {
  const int row = blockIdx.x;
  const int tid = threadIdx.x;
  const float4* xr = (const float4*)(x + (size_t)row * DD);
  float4 v[5];
  float m = 0.f;
#pragma unroll
  for (int r = 0; r < 5; ++r) {
    v[r] = xr[tid + r * 256];
    m = fmaxf(m, fmaxf(fmaxf(fabsf(v[r].x), fabsf(v[r].y)),
                       fmaxf(fabsf(v[r].z), fabsf(v[r].w))));
  }
  __shared__ float redf[4];
  __shared__ int redi[4];
  float wm = wave_max64(m);
  int wid = tid >> 6, lane = tid & 63;
  if (lane == 0) redf[wid] = wm;
  __syncthreads();
  float mm = fmaxf(fmaxf(redf[0], redf[1]), fmaxf(redf[2], redf[3]));
  float s = fmaxf(mm / 127.0f, 1e-8f);

  int lsum = 0;
  int* qr = (int*)(q + (size_t)row * DD);
#pragma unroll
  for (int r = 0; r < 5; ++r) {
    float a = fminf(127.f, fmaxf(-127.f, rintf(v[r].x / s)));
    float b = fminf(127.f, fmaxf(-127.f, rintf(v[r].y / s)));
    float c = fminf(127.f, fmaxf(-127.f, rintf(v[r].z / s)));
    float d = fminf(127.f, fmaxf(-127.f, rintf(v[r].w / s)));
    int ia = (int)a, ib = (int)b, ic = (int)c, id = (int)d;
    lsum += ia + ib + ic + id;
    qr[tid + r * 256] = (ia & 0xff) | ((ib & 0xff) << 8) | ((ic & 0xff) << 16) |
                        ((id & 0xff) << 24);
  }
  int wsum = wave_sum64(lsum);
  if (lane == 0) redi[wid] = wsum;
  __syncthreads();
  if (tid == 0) {
    s_out[row] = s;
    sum_out[row] = (float)(redi[0] + redi[1] + redi[2] + redi[3]);
  }
}

// ---------------- per-token dynamic quant of g [TT, HH] ----------------
__global__ __launch_bounds__(256) void quant_g(const float* __restrict__ g,
                                               int8_t* __restrict__ q,
                                               float* __restrict__ s_out,
                                               float* __restrict__ sum_out) {
  const int row = blockIdx.x;
  const int tid = threadIdx.x;
  const float4* gr = (const float4*)(g + (size_t)row * HH);
  float4 v[14];
  float m = 0.f;
#pragma unroll
  for (int r = 0; r < 14; ++r) {
    int idx = r * 256 + tid;
    if (idx < HH / 4) {
      v[r] = gr[idx];
      m = fmaxf(m, fmaxf(fmaxf(fabsf(v[r].x), fabsf(v[r].y)),
                         fmaxf(fabsf(v[r].z), fabsf(v[r].w))));
    }
  }
  __shared__ float redf[4];
  __shared__ int redi[4];
  float wm = wave_max64(m);
  int wid = tid >> 6, lane = tid & 63;
  if (lane == 0) redf[wid] = wm;
  __syncthreads();
  float mm = fmaxf(fmaxf(redf[0], redf[1]), fmaxf(redf[2], redf[3]));
  float s = fmaxf(mm / 127.0f, 1e-8f);

  int lsum = 0;
  int* qr = (int*)(q + (size_t)row * HH);
#pragma unroll
  for (int r = 0; r < 14; ++r) {
    int idx = r * 256 + tid;
    if (idx < HH / 4) {
      float a = fminf(127.f, fmaxf(-127.f, rintf(v[r].x / s)));
      float b = fminf(127.f, fmaxf(-127.f, rintf(v[r].y / s)));
      float c = fminf(127.f, fmaxf(-127.f, rintf(v[r].z / s)));
      float d = fminf(127.f, fmaxf(-127.f, rintf(v[r].w / s)));
      int ia = (int)a, ib = (int)b, ic = (int)c, id = (int)d;
      lsum += ia + ib + ic + id;
      qr[idx] = (ia & 0xff) | ((ib & 0xff) << 8) | ((ic & 0xff) << 16) |
                ((id & 0xff) << 24);
    }
  }
  int wsum = wave_sum64(lsum);
  if (lane == 0) redi[wid] = wsum;
  __syncthreads();
  if (tid == 0) {
    s_out[row] = s;
    sum_out[row] = (float)(redi[0] + redi[1] + redi[2] + redi[3]);
  }
}

// ---------------- int8 GEMM: C[t,j] = sum_k A[t,k]*B[j,k], fused dequant (+GELU) ----------------
// A: [M,K] int8 row-major (activations). B: [N,K] int8 row-major (weights, code-128).
// out = sx[t]*ws[j]*(acc - (zp[j]-128)*sumx[t]) + bias[j]; optional exact GELU.
// REQUIRES gridDim.y == 64 and gridDim.x % 8 == 0 (XCD swizzle assumption).
template <bool GELU>
__global__ __launch_bounds__(256) void gemm_i8(
    const int8_t* __restrict__ A, const int8_t* __restrict__ B,
    float* __restrict__ OUT, const float* __restrict__ sx,
    const float* __restrict__ sumx, const float* __restrict__ wsc,
    const float* __restrict__ wzp, const float* __restrict__ bias, int M,
    int N, int K) {
  alignas(16) __shared__ int8_t sA[128 * 64];
  alignas(16) __shared__ int8_t sB[128 * 64];
  const int tid = threadIdx.x;
  const int lane = tid & 63;
  const int wid = tid >> 6;

  // XCD-aware swizzle (T1): hardware XCD = bid%8 gets a contiguous chunk of
  // 8 tile-rows; within the chunk iterate column-major so co-resident blocks
  // on one XCD share each B-panel from L2 while 8 A-panels stay resident.
  // Bijective because gridDim.y==64 and total grid % 64 == 0.
  const int bid = blockIdx.y * gridDim.x + blockIdx.x;
  const int xcd = bid & 7;
  const int t = bid >> 3;
  const int tx = t >> 3;
  const int ty = xcd * 8 + (t & 7);
  const int tm0 = ty * 128;
  const int tn0 = tx * 128;

  const int wm = wid >> 1;  // 0..1
  const int wn = wid & 1;   // 0..1
  const int lr = lane & 15;
  const int lg = lane >> 4;

  // fragment LDS byte offsets (swizzled), fixed across K loop
  int aoff[4], boff[4];
#pragma unroll
  for (int i = 0; i < 4; ++i) {
    int rowA = wm * 64 + i * 16 + lr;
    int swA = (rowA ^ (rowA >> 2)) & 3;
    aoff[i] = rowA * 64 + ((lg ^ swA) << 4);
    int rowB = wn * 64 + i * 16 + lr;
    int swB = (rowB ^ (rowB >> 2)) & 3;
    boff[i] = rowB * 64 + ((lg ^ swB) << 4);
  }

  // staging source (row, swizzled col) per round, fixed except k0
  int st_row[2], st_col[2];
#pragma unroll
  for (int r = 0; r < 2; ++r) {
    int o = tid * 16 + r * 4096;
    int row = o >> 6;
    int sp = (o >> 4) & 3;
    int sw = (row ^ (row >> 2)) & 3;
    st_row[r] = row;
    st_col[r] = ((sp ^ sw) << 4);
  }

  v4i acc[4][4];
  v4i zero = {0, 0, 0, 0};
#pragma unroll
  for (int i = 0; i < 4; ++i)
#pragma unroll
    for (int j = 0; j < 4; ++j) acc[i][j] = zero;

  const size_t Ks = (size_t)K;
  for (int k0 = 0; k0 < K; k0 += 64) {
#pragma unroll
    for (int r = 0; r < 2; ++r) {
      const int8_t* srcA = A + (size_t)(tm0 + st_row[r]) * Ks + k0 + st_col[r];
      __builtin_amdgcn_global_load_lds(AS1(srcA), AS3(sA + wid * 1024 + r * 4096), 16, 0, 0);
      const int8_t* srcB = B + (size_t)(tn0 + st_row[r]) * Ks + k0 + st_col[r];
      __builtin_amdgcn_global_load_lds(AS1(srcB), AS3(sB + wid * 1024 + r * 4096), 16, 0, 0);
    }
    __syncthreads();
    v4i af[4], bf[4];
#pragma unroll
    for (int i = 0; i < 4; ++i) af[i] = *(const v4i*)(sA + aoff[i]);
#pragma unroll
    for (int j = 0; j < 4; ++j) bf[j] = *(const v4i*)(sB + boff[j]);
#pragma unroll
    for (int i = 0; i < 4; ++i)
#pragma unroll
      for (int j = 0; j < 4; ++j)
        acc[i][j] =
            __builtin_amdgcn_mfma_i32_16x16x64_i8(af[i], bf[j], acc[i][j], 0, 0, 0);
    __syncthreads();
  }

  // epilogue: C element (row, col): col = lane&15, row = (lane>>4)*4 + reg
#pragma unroll
  for (int j = 0; j < 4; ++j) {
    int col = tn0 + wn * 64 + j * 16 + lr;
    float wsj = wsc[col];
    float zpj = wzp[col] - 128.0f;
    float bj = bias[col];
#pragma unroll
    for (int i = 0; i < 4; ++i) {
#pragma unroll
      for (int rg = 0; rg < 4; ++rg) {
        int row = tm0 + wm * 64 + i * 16 + lg * 4 + rg;
        float a = (float)acc[i][j][rg];
        float o = sx[row] * wsj * (a - zpj * sumx[row]) + bj;
        if (GELU) o = 0.5f * o * (1.0f + erff(o * 0.70710678118654752f));
        OUT[(size_t)row * N + col] = o;
      }
    }
  }
}

extern "C" void kernel_launch(void* const* d_in, const int* in_sizes, int n_in,
                              void* d_out, int out_size, void* d_ws,
                              size_t ws_size, hipStream_t stream) {
  const float* x = (const float*)d_in[0];
  const int* w1q = (const int*)d_in[1];
  const float* w1s = (const float*)d_in[2];
  const float* w1zp = (const float*)d_in[3];
  const float* b1 = (const float*)d_in[4];
  const int* w2q = (const int*)d_in[5];
  const float* w2s = (const float*)d_in[6];
  const float* w2zp = (const float*)d_in[7];
  const float* b2 = (const float*)d_in[8];
  float* out = (float*)d_out;

  char* base = (char*)d_ws;
  size_t off = 0;
  auto take = [&](size_t b) {
    char* p = base + off;
    off += (b + 255) & ~(size_t)255;
    return p;
  };
  int8_t* q1 = (int8_t*)take((size_t)TT * DD);
  int8_t* q2 = (int8_t*)take((size_t)TT * HH);
  int8_t* w1b = (int8_t*)take((size_t)HH * DD);
  int8_t* w2b = (int8_t*)take((size_t)DD * HH);
  float* g = (float*)take((size_t)TT * HH * 4);
  float* s1 = (float*)take((size_t)TT * 4);
  float* sum1 = (float*)take((size_t)TT * 4);
  float* s2 = (float*)take((size_t)TT * 4);
  float* sum2 = (float*)take((size_t)TT * 4);

  hipLaunchKernelGGL(cvt_w, dim3(2048), dim3(256), 0, stream, w1q, w1b,
                     (int)((size_t)HH * DD / 16));
  hipLaunchKernelGGL(quant_x, dim3(TT), dim3(256), 0, stream, x, q1, s1, sum1);
  hipLaunchKernelGGL((gemm_i8<true>), dim3(HH / 128, TT / 128), dim3(256), 0,
                     stream, q1, w1b, g, s1, sum1, w1s, w1zp, b1, TT, HH, DD);
  hipLaunchKernelGGL(cvt_w, dim3(2048), dim3(256), 0, stream, w2q, w2b,
                     (int)((size_t)DD * HH / 16));
  hipLaunchKernelGGL(quant_g, dim3(TT), dim3(256), 0, stream, g, q2, s2, sum2);
  hipLaunchKernelGGL((gemm_i8<false>), dim3(DD / 128, TT / 128), dim3(256), 0,
                     stream, q2, w2b, out, s2, sum2, w2s, w2zp, b2, TT, DD, HH);
}

// Round 3
// 2097.824 us; speedup vs baseline: 1.3990x; 1.3990x over previous
//
#include <hip/hip_runtime.h>
#include <stdint.h>

#define TT 8192
#define DD 5120
#define HH 13824

typedef int v4i __attribute__((ext_vector_type(4)));

#define AS1(p) ((const __attribute__((address_space(1))) void*)(p))
#define AS3(p) ((__attribute__((address_space(3))) void*)(p))

__device__ __forceinline__ float wave_max64(float v) {
#pragma unroll
  for (int off = 32; off > 0; off >>= 1)
    v = fmaxf(v, __shfl_xor(v, off, 64));
  return v;
}
__device__ __forceinline__ int wave_sum64(int v) {
#pragma unroll
  for (int off = 32; off > 0; off >>= 1)
    v += __shfl_xor(v, off, 64);
  return v;
}

// ---------------- weight convert: int32 codes (0..255) -> int8 (code-128) ----------------
__global__ __launch_bounds__(256) void cvt_w(const int* __restrict__ w,
                                             int8_t* __restrict__ o, int n16) {
  const int4* w4 = (const int4*)w;
  int4* o4 = (int4*)o;
  int i = blockIdx.x * blockDim.x + threadIdx.x;
  int stride = gridDim.x * blockDim.x;
  for (; i < n16; i += stride) {
    int4 a = w4[(size_t)i * 4 + 0];
    int4 b = w4[(size_t)i * 4 + 1];
    int4 c = w4[(size_t)i * 4 + 2];
    int4 d = w4[(size_t)i * 4 + 3];
    int4 r;
    r.x = ((a.x - 128) & 0xff) | (((a.y - 128) & 0xff) << 8) |
          (((a.z - 128) & 0xff) << 16) | (((a.w - 128) & 0xff) << 24);
    r.y = ((b.x - 128) & 0xff) | (((b.y - 128) & 0xff) << 8) |
          (((b.z - 128) & 0xff) << 16) | (((b.w - 128) & 0xff) << 24);
    r.z = ((c.x - 128) & 0xff) | (((c.y - 128) & 0xff) << 8) |
          (((c.z - 128) & 0xff) << 16) | (((c.w - 128) & 0xff) << 24);
    r.w = ((d.x - 128) & 0xff) | (((d.y - 128) & 0xff) << 8) |
          (((d.z - 128) & 0xff) << 16) | (((d.w - 128) & 0xff) << 24);
    o4[i] = r;
  }
}

// ---------------- per-token dynamic quant of x [TT, DD] ----------------
__global__ __launch_bounds__(256) void quant_x(const float* __restrict__ x,
                                               int8_t* __restrict__ q,
                                               float* __restrict__ s_out,
                                               float* __restrict__ sum_out) {
  const int row = blockIdx.x;
  const int tid = threadIdx.x;
  const float4* xr = (const float4*)(x + (size_t)row * DD);
  float4 v[5];
  float m = 0.f;
#pragma unroll
  for (int r = 0; r < 5; ++r) {
    v[r] = xr[tid + r * 256];
    m = fmaxf(m, fmaxf(fmaxf(fabsf(v[r].x), fabsf(v[r].y)),
                       fmaxf(fabsf(v[r].z), fabsf(v[r].w))));
  }
  __shared__ float redf[4];
  __shared__ int redi[4];
  float wm = wave_max64(m);
  int wid = tid >> 6, lane = tid & 63;
  if (lane == 0) redf[wid] = wm;
  __syncthreads();
  float mm = fmaxf(fmaxf(redf[0], redf[1]), fmaxf(redf[2], redf[3]));
  float s = fmaxf(mm / 127.0f, 1e-8f);

  int lsum = 0;
  int* qr = (int*)(q + (size_t)row * DD);
#pragma unroll
  for (int r = 0; r < 5; ++r) {
    float a = fminf(127.f, fmaxf(-127.f, rintf(v[r].x / s)));
    float b = fminf(127.f, fmaxf(-127.f, rintf(v[r].y / s)));
    float c = fminf(127.f, fmaxf(-127.f, rintf(v[r].z / s)));
    float d = fminf(127.f, fmaxf(-127.f, rintf(v[r].w / s)));
    int ia = (int)a, ib = (int)b, ic = (int)c, id = (int)d;
    lsum += ia + ib + ic + id;
    qr[tid + r * 256] = (ia & 0xff) | ((ib & 0xff) << 8) | ((ic & 0xff) << 16) |
                        ((id & 0xff) << 24);
  }
  int wsum = wave_sum64(lsum);
  if (lane == 0) redi[wid] = wsum;
  __syncthreads();
  if (tid == 0) {
    s_out[row] = s;
    sum_out[row] = (float)(redi[0] + redi[1] + redi[2] + redi[3]);
  }
}

// ---------------- per-token dynamic quant of g [TT, HH] ----------------
__global__ __launch_bounds__(256) void quant_g(const float* __restrict__ g,
                                               int8_t* __restrict__ q,
                                               float* __restrict__ s_out,
                                               float* __restrict__ sum_out) {
  const int row = blockIdx.x;
  const int tid = threadIdx.x;
  const float4* gr = (const float4*)(g + (size_t)row * HH);
  float4 v[14];
  float m = 0.f;
#pragma unroll
  for (int r = 0; r < 14; ++r) {
    int idx = r * 256 + tid;
    if (idx < HH / 4) {
      v[r] = gr[idx];
      m = fmaxf(m, fmaxf(fmaxf(fabsf(v[r].x), fabsf(v[r].y)),
                         fmaxf(fabsf(v[r].z), fabsf(v[r].w))));
    }
  }
  __shared__ float redf[4];
  __shared__ int redi[4];
  float wm = wave_max64(m);
  int wid = tid >> 6, lane = tid & 63;
  if (lane == 0) redf[wid] = wm;
  __syncthreads();
  float mm = fmaxf(fmaxf(redf[0], redf[1]), fmaxf(redf[2], redf[3]));
  float s = fmaxf(mm / 127.0f, 1e-8f);

  int lsum = 0;
  int* qr = (int*)(q + (size_t)row * HH);
#pragma unroll
  for (int r = 0; r < 14; ++r) {
    int idx = r * 256 + tid;
    if (idx < HH / 4) {
      float a = fminf(127.f, fmaxf(-127.f, rintf(v[r].x / s)));
      float b = fminf(127.f, fmaxf(-127.f, rintf(v[r].y / s)));
      float c = fminf(127.f, fmaxf(-127.f, rintf(v[r].z / s)));
      float d = fminf(127.f, fmaxf(-127.f, rintf(v[r].w / s)));
      int ia = (int)a, ib = (int)b, ic = (int)c, id = (int)d;
      lsum += ia + ib + ic + id;
      qr[idx] = (ia & 0xff) | ((ib & 0xff) << 8) | ((ic & 0xff) << 16) |
                ((id & 0xff) << 24);
    }
  }
  int wsum = wave_sum64(lsum);
  if (lane == 0) redi[wid] = wsum;
  __syncthreads();
  if (tid == 0) {
    s_out[row] = s;
    sum_out[row] = (float)(redi[0] + redi[1] + redi[2] + redi[3]);
  }
}

// ================= 256x256 8-phase i8 GEMM (T2+T3+T4+T5 port) =================
// C[t,j] = sum_k A[t,k]*B[j,k]; A:[M,K] i8, B:[N,K] i8 (codes-128).
// 512 thr = 8 waves (2M x 4N); BK=128 B; LDS 128 KiB = 2 K-tile buffers
//   buf b: A at b*65536, B at b*65536+32768; rows of 128 B.
// Swizzle: LDS[row][c'] holds Mat[row][c' ^ ((row&7)<<4)] (stage side:
//   linear LDS dest, inverse-permuted global col; read side: same XOR).
// Staging granules: A quarter q = rows {q*32..+32} u {128+q*32..+32} (1 ld/thr),
//   B half h = rows {h*128..+128} (2 ld/thr). 16 loads/thr per iter (2 K-tiles).
// Steady-state issue: p0:A(2j+1)q3 | p1:B(2j+2)h0,Aq0 | p2:Bh1,Aq1 | p3:Aq2 |
//   p4:Aq3 | p5:A(2j+3)q0 | p6:B(2j+3)h0,Aq1 | p7:Bh1,Aq2.
// vmcnt(7) at p3/p7 only: audited — every granule has >=8 younger issues at
//   its deadline wait; regions staged only after their death barrier.
#define BAR_() __builtin_amdgcn_s_barrier()
#define WAITV7_() asm volatile("s_waitcnt vmcnt(7)" ::: "memory")
#define WAITLGKM_() asm volatile("s_waitcnt lgkmcnt(0)" ::: "memory")

#define STAGE_AQ(B_, KT_, Q_)                                                  \
  __builtin_amdgcn_global_load_lds(                                            \
      AS1(Aptr + (size_t)(tm0 + aq_row0 + (Q_)*32) * Ks + (size_t)(KT_)*128 +  \
          st_c),                                                               \
      AS3(lds + (B_)*65536 + a_dst_w + (Q_)*4096), 16, 0, 0)

#define STAGE_BH(B_, KT_, H_, R_)                                              \
  __builtin_amdgcn_global_load_lds(                                            \
      AS1(Bptr + (size_t)(tn0 + (H_)*128 + (R_)*64 + b_row0) * Ks +            \
          (size_t)(KT_)*128 + st_c),                                           \
      AS3(lds + (B_)*65536 + 32768 + (H_)*16384 + (R_)*8192 + wid * 1024), 16, \
      0, 0)

#define DS_A(B_, Q_)                                                           \
  {                                                                            \
    const int8_t* _pa = &lds[(B_)*65536 + aRowOff + (Q_)*4096];                \
    af0 = *(const v4i*)(_pa + col0);                                           \
    af1 = *(const v4i*)(_pa + col1);                                           \
    af2 = *(const v4i*)(_pa + 2048 + col0);                                    \
    af3 = *(const v4i*)(_pa + 2048 + col1);                                    \
  }

#define DS_B(B_)                                                               \
  {                                                                            \
    const int8_t* _pb = &lds[(B_)*65536 + 32768 + bRowOff];                    \
    bf0 = *(const v4i*)(_pb + col0);                                           \
    bf1 = *(const v4i*)(_pb + col1);                                           \
    bf2 = *(const v4i*)(_pb + 2048 + col0);                                    \
    bf3 = *(const v4i*)(_pb + 2048 + col1);                                    \
    bf4 = *(const v4i*)(_pb + 4096 + col0);                                    \
    bf5 = *(const v4i*)(_pb + 4096 + col1);                                    \
    bf6 = *(const v4i*)(_pb + 6144 + col0);                                    \
    bf7 = *(const v4i*)(_pb + 6144 + col1);                                    \
  }

#define MM(A_, B_, C_) C_ = __builtin_amdgcn_mfma_i32_16x16x64_i8(A_, B_, C_, 0, 0, 0)
#define MFMA_J(Q_, J_, BF0_, BF1_)                                             \
  MM(af0, BF0_, acc[(Q_)*2][J_]);                                              \
  MM(af1, BF1_, acc[(Q_)*2][J_]);                                              \
  MM(af2, BF0_, acc[(Q_)*2 + 1][J_]);                                          \
  MM(af3, BF1_, acc[(Q_)*2 + 1][J_]);
#define MFMA16(Q_)                                                             \
  MFMA_J(Q_, 0, bf0, bf1)                                                      \
  MFMA_J(Q_, 1, bf2, bf3)                                                      \
  MFMA_J(Q_, 2, bf4, bf5)                                                      \
  MFMA_J(Q_, 3, bf6, bf7)

#define PH(B_, Q_)                                                             \
  BAR_();                                                                      \
  WAITLGKM_();                                                                 \
  __builtin_amdgcn_s_setprio(1);                                               \
  MFMA16(Q_);                                                                  \
  __builtin_amdgcn_s_setprio(0)

template <bool GELU>
__global__ __launch_bounds__(512, 2) void gemm8p(
    const int8_t* __restrict__ Aptr, const int8_t* __restrict__ Bptr,
    float* __restrict__ OUT, const float* __restrict__ sx,
    const float* __restrict__ sumx, const float* __restrict__ wsc,
    const float* __restrict__ wzp, const float* __restrict__ bias, int M,
    int N, int K) {
  extern __shared__ int8_t lds[];
  const int tid = threadIdx.x;
  const int lane = tid & 63;
  const int wid = tid >> 6;

  // XCD swizzle (requires gridDim.y==32, total%8==0): XCD gets 4 tile-rows,
  // column-major within chunk -> co-resident blocks share B-panels in L2.
  const int bid = blockIdx.y * gridDim.x + blockIdx.x;
  const int t = bid >> 3;
  const int ty = (bid & 7) * 4 + (t & 3);
  const int tx = t >> 2;
  const int tm0 = ty * 256;
  const int tn0 = tx * 256;

  const int wm = wid >> 2;  // 0..1
  const int wn = wid & 3;   // 0..3

  // read-side addresses
  const int col0 = (((lane >> 4) ^ (lane & 7)) << 4);
  const int col1 = col0 ^ 64;
  const int aRowOff = (wm * 128 + (lane & 15)) * 128;
  const int bRowOff = (wn * 64 + (lane & 15)) * 128;

  // stage-side addresses
  const int st_c = (((tid & 7) ^ ((tid >> 3) & 7)) << 4);  // inverse swizzle
  const int aq_row0 = ((tid & 255) >> 3) + (tid >> 8) * 128;
  const int b_row0 = tid >> 3;
  const int a_dst_w = (wid >> 2) * 16384 + (wid & 3) * 1024;  // wave-uniform

  const size_t Ks = (size_t)K;
  const int NT = K >> 7;      // K-tiles of 128
  const int NITER = K >> 8;   // 2 K-tiles per iteration

  v4i acc[8][4];
  v4i zero = {0, 0, 0, 0};
#pragma unroll
  for (int i = 0; i < 8; ++i)
#pragma unroll
    for (int j = 0; j < 4; ++j) acc[i][j] = zero;
  v4i af0, af1, af2, af3;
  v4i bf0, bf1, bf2, bf3, bf4, bf5, bf6, bf7;

  // ---- prologue: kt0 full (8 loads) + kt1 partial (7 loads) ----
  STAGE_AQ(0, 0, 0); STAGE_AQ(0, 0, 1); STAGE_AQ(0, 0, 2); STAGE_AQ(0, 0, 3);
  STAGE_BH(0, 0, 0, 0); STAGE_BH(0, 0, 0, 1);
  STAGE_BH(0, 0, 1, 0); STAGE_BH(0, 0, 1, 1);
  STAGE_AQ(1, 1, 0);
  STAGE_BH(1, 1, 0, 0); STAGE_BH(1, 1, 0, 1);
  STAGE_AQ(1, 1, 1);
  STAGE_BH(1, 1, 1, 0); STAGE_BH(1, 1, 1, 1);
  STAGE_AQ(1, 1, 2);
  WAITV7_();
  BAR_();

  for (int j = 0; j < NITER; ++j) {
    const int kt1 = 2 * j + 1;
    int ka = 2 * j + 2;
    if (ka >= NT) ka -= NT;  // last-iter wrap: wasted but valid loads
    int kb = 2 * j + 3;
    if (kb >= NT) kb -= NT;
    // p0: compute buf0 {B all + A q0}
    DS_B(0) DS_A(0, 0)
    STAGE_AQ(1, kt1, 3);
    PH(0, 0);
    BAR_();
    // p1
    DS_A(0, 1)
    STAGE_BH(0, ka, 0, 0); STAGE_BH(0, ka, 0, 1); STAGE_AQ(0, ka, 0);
    PH(0, 1);
    BAR_();
    // p2
    DS_A(0, 2)
    STAGE_BH(0, ka, 1, 0); STAGE_BH(0, ka, 1, 1); STAGE_AQ(0, ka, 1);
    PH(0, 2);
    BAR_();
    // p3 (K-tile boundary)
    DS_A(0, 3)
    STAGE_AQ(0, ka, 2);
    PH(0, 3);
    WAITV7_();
    BAR_();
    // p4: compute buf1
    DS_B(1) DS_A(1, 0)
    STAGE_AQ(0, ka, 3);
    PH(1, 0);
    BAR_();
    // p5
    DS_A(1, 1)
    STAGE_AQ(1, kb, 0);
    PH(1, 1);
    BAR_();
    // p6
    DS_A(1, 2)
    STAGE_BH(1, kb, 0, 0); STAGE_BH(1, kb, 0, 1); STAGE_AQ(1, kb, 1);
    PH(1, 2);
    BAR_();
    // p7 (K-tile boundary)
    DS_A(1, 3)
    STAGE_BH(1, kb, 1, 0); STAGE_BH(1, kb, 1, 1); STAGE_AQ(1, kb, 2);
    PH(1, 3);
    WAITV7_();
    BAR_();
  }

  // ---- epilogue: dequant (+GELU) and store ----
#pragma unroll
  for (int jj = 0; jj < 4; ++jj) {
    int col = tn0 + wn * 64 + jj * 16 + (lane & 15);
    float wsj = wsc[col];
    float zpj = wzp[col] - 128.0f;
    float bj = bias[col];
#pragma unroll
    for (int i = 0; i < 8; ++i) {
#pragma unroll
      for (int rg = 0; rg < 4; ++rg) {
        int row = tm0 + wm * 128 + i * 16 + (lane >> 4) * 4 + rg;
        float a = (float)acc[i][jj][rg];
        float o = sx[row] * wsj * (a - zpj * sumx[row]) + bj;
        if (GELU) o = 0.5f * o * (1.0f + erff(o * 0.70710678118654752f));
        OUT[(size_t)row * N + col] = o;
      }
    }
  }
}

extern "C" void kernel_launch(void* const* d_in, const int* in_sizes, int n_in,
                              void* d_out, int out_size, void* d_ws,
                              size_t ws_size, hipStream_t stream) {
  const float* x = (const float*)d_in[0];
  const int* w1q = (const int*)d_in[1];
  const float* w1s = (const float*)d_in[2];
  const float* w1zp = (const float*)d_in[3];
  const float* b1 = (const float*)d_in[4];
  const int* w2q = (const int*)d_in[5];
  const float* w2s = (const float*)d_in[6];
  const float* w2zp = (const float*)d_in[7];
  const float* b2 = (const float*)d_in[8];
  float* out = (float*)d_out;

  char* base = (char*)d_ws;
  size_t off = 0;
  auto take = [&](size_t b) {
    char* p = base + off;
    off += (b + 255) & ~(size_t)255;
    return p;
  };
  int8_t* q1 = (int8_t*)take((size_t)TT * DD);
  int8_t* q2 = (int8_t*)take((size_t)TT * HH);
  int8_t* w1b = (int8_t*)take((size_t)HH * DD);
  int8_t* w2b = (int8_t*)take((size_t)DD * HH);
  float* g = (float*)take((size_t)TT * HH * 4);
  float* s1 = (float*)take((size_t)TT * 4);
  float* sum1 = (float*)take((size_t)TT * 4);
  float* s2 = (float*)take((size_t)TT * 4);
  float* sum2 = (float*)take((size_t)TT * 4);

  hipLaunchKernelGGL(cvt_w, dim3(2048), dim3(256), 0, stream, w1q, w1b,
                     (int)((size_t)HH * DD / 16));
  hipLaunchKernelGGL(quant_x, dim3(TT), dim3(256), 0, stream, x, q1, s1, sum1);
  hipLaunchKernelGGL((gemm8p<true>), dim3(HH / 256, TT / 256), dim3(512),
                     131072, stream, q1, w1b, g, s1, sum1, w1s, w1zp, b1, TT,
                     HH, DD);
  hipLaunchKernelGGL(cvt_w, dim3(2048), dim3(256), 0, stream, w2q, w2b,
                     (int)((size_t)DD * HH / 16));
  hipLaunchKernelGGL(quant_g, dim3(TT), dim3(256), 0, stream, g, q2, s2, sum2);
  hipLaunchKernelGGL((gemm8p<false>), dim3(DD / 256, TT / 256), dim3(512),
                     131072, stream, q2, w2b, out, s2, sum2, w2s, w2zp, b2, TT,
                     DD, HH);
}